// Round 11
// baseline (4015.340 us; speedup 1.0000x reference)
//
#include <hip/hip_runtime.h>

#define TT 512
#define BB 1024
#define FF 32
#define HH 64
#define GG 256   // 4*H gates per direction

// Static device scratch (ws_size-independent). Fully overwritten every call.
__device__ float g_h1[(size_t)TT * BB * 2 * HH];   // [T][B][128] layer-1 input, 256 MB
__device__ float g_pre0[(size_t)2 * TT * BB * GG]; // [dir][T][B][256] layer-0 pre-gates, 1.07 GB
__device__ float g_pre1[(size_t)TT * BB * GG];     // [T][B][256] layer-1 fwd pre-gates, 537 MB
__device__ float g_hf[(size_t)BB * HH];            // [B][64] final fwd h of layer1

__device__ __forceinline__ float fsigm(float x) {
    float e = __builtin_amdgcn_exp2f(x * -1.44269504088896f);
    return __builtin_amdgcn_rcpf(1.0f + e);
}
__device__ __forceinline__ float ftanh(float x) {
    float e = __builtin_amdgcn_exp2f(x * -2.88539008177793f);
    return 2.0f * __builtin_amdgcn_rcpf(1.0f + e) - 1.0f;
}

// 2-batch MAC on one weight quad via wave-uniform LDS broadcast (conflict-free,
// LDS pipe, no VALU readlane overhead — r10's 256 readlanes/step were the
// 5.8 cyc/inst stall: VALU->SGPR->VALU hazards).
#define HM2L(J4, WQ) do{                                                      \
    float4 h0_ = hq[(J4)];     /* batch 0, uniform addr -> broadcast */       \
    float4 h1_ = hq[16+(J4)];  /* batch 1 */                                  \
    acc0 += h0_.x*(WQ).x + h0_.y*(WQ).y + h0_.z*(WQ).z + h0_.w*(WQ).w;        \
    acc1 += h1_.x*(WQ).x + h1_.y*(WQ).y + h1_.z*(WQ).z + h1_.w*(WQ).w;        \
}while(0)
#define HM1L(J4, WQ) do{                                                      \
    float4 h0_ = hq[(J4)];                                                    \
    acc0 += h0_.x*(WQ).x + h0_.y*(WQ).y + h0_.z*(WQ).z + h0_.w*(WQ).w;        \
}while(0)

// ---------------------------------------------------------------------------
// Layer-0 input pre-gates (unchanged from r10).
// ---------------------------------------------------------------------------
__global__ __launch_bounds__(256, 4) void pre_gemm0(
    const float* __restrict__ x,      // [B][T][F]
    const float* __restrict__ w_ih,   // [2][G][F]
    const float* __restrict__ b_ih,
    const float* __restrict__ b_hh)
{
    const int tid = threadIdx.x;          // gate
    const int b   = blockIdx.x >> 1;
    const int dir = blockIdx.x & 1;

    __shared__ __align__(16) float4 w4[8 * 256];    // [kq][gate], 32 KB
    __shared__ __align__(16) float xbuf[2][256];    // 8 t-rows x 32 f, dbuf

    const float4* wsrc = (const float4*)(w_ih + ((size_t)dir * GG + tid) * FF);
#pragma unroll
    for (int kq = 0; kq < 8; ++kq) w4[kq * 256 + tid] = wsrc[kq];
    const float bias = b_ih[dir * GG + tid] + b_hh[dir * GG + tid];

    const float* xbase = x + (size_t)b * TT * FF;
    xbuf[0][tid] = xbase[tid];            // tile 0 (rows 0..7), coalesced
    const size_t OS = (size_t)BB * GG;

    for (int tc = 0; tc < 64; ++tc) {
        const int cur = tc & 1;
        __syncthreads();   // xbuf[cur] ready; prev reads of xbuf[1-cur] done

        float vnext = 0.f;
        if (tc + 1 < 64) vnext = xbase[(tc + 1) * 256 + tid];   // coalesced

        float a0 = bias, a1 = bias, a2 = bias, a3 = bias,
              a4 = bias, a5 = bias, a6 = bias, a7 = bias;
#pragma unroll
        for (int kq = 0; kq < 8; ++kq) {
            float4 wq = w4[kq * 256 + tid];
            const float4* xr = (const float4*)xbuf[cur];
            float4 q;
            q = xr[0 * 8 + kq]; a0 += q.x*wq.x + q.y*wq.y + q.z*wq.z + q.w*wq.w;
            q = xr[1 * 8 + kq]; a1 += q.x*wq.x + q.y*wq.y + q.z*wq.z + q.w*wq.w;
            q = xr[2 * 8 + kq]; a2 += q.x*wq.x + q.y*wq.y + q.z*wq.z + q.w*wq.w;
            q = xr[3 * 8 + kq]; a3 += q.x*wq.x + q.y*wq.y + q.z*wq.z + q.w*wq.w;
            q = xr[4 * 8 + kq]; a4 += q.x*wq.x + q.y*wq.y + q.z*wq.z + q.w*wq.w;
            q = xr[5 * 8 + kq]; a5 += q.x*wq.x + q.y*wq.y + q.z*wq.z + q.w*wq.w;
            q = xr[6 * 8 + kq]; a6 += q.x*wq.x + q.y*wq.y + q.z*wq.z + q.w*wq.w;
            q = xr[7 * 8 + kq]; a7 += q.x*wq.x + q.y*wq.y + q.z*wq.z + q.w*wq.w;
        }
        float* op = g_pre0 + (((size_t)dir * TT + tc * 8) * BB + b) * GG + tid;
        op[0] = a0; op[1 * OS] = a1; op[2 * OS] = a2; op[3 * OS] = a3;
        op[4 * OS] = a4; op[5 * OS] = a5; op[6 * OS] = a6; op[7 * OS] = a7;

        if (tc + 1 < 64) xbuf[1 - cur][tid] = vnext;
    }
}

// ---------------------------------------------------------------------------
// Layer 0 recurrent-only scan, v3: LDS-broadcast operands.
// 1024 blocks (dir = bid&1, 2 batches) x 256 thr (thread = gate).
// Weight quads 0..11 in regs (48 VGPR), 12..15 in 16 KB LDS; h in LDS,
// read at wave-uniform addresses (broadcast, conflict-free).
// ---------------------------------------------------------------------------
__global__ __launch_bounds__(256, 4) void lstm_layer0_scan(
    const float* __restrict__ w_hh)   // [2][G][64]
{
    const int tid  = threadIdx.x;
    const int dir  = blockIdx.x & 1;
    const int b0   = (blockIdx.x >> 1) * 2;

    __shared__ __align__(16) float4 wlds[4 * 256];   // quads 12..15, 16 KB
    __shared__ float gact[2][GG];
    __shared__ __align__(16) float hbuf[128];        // [b][j] -> b*64+j

    const float4* wsrc = (const float4*)(w_hh + (size_t)dir * GG * HH) + (size_t)tid * 16;
    float4 w0 = wsrc[0],  w1 = wsrc[1],  w2 = wsrc[2],  w3 = wsrc[3],
           w4 = wsrc[4],  w5 = wsrc[5],  w6 = wsrc[6],  w7 = wsrc[7],
           w8 = wsrc[8],  w9 = wsrc[9],  w10 = wsrc[10], w11 = wsrc[11];
#pragma unroll
    for (int i = 0; i < 4; ++i) wlds[i * 256 + tid] = wsrc[12 + i];

    float c_reg = 0.f;
    const int cb = (tid >> 6) & 1, cj = tid & 63;    // cell role (tid < 128)
    const bool is_g = ((tid >> 6) == 2);             // gate 128..191 -> tanh
    if (tid < 128) hbuf[tid] = 0.f;                  // zero initial state
    __syncthreads();   // wlds + hbuf ready

    const size_t DOFF = (size_t)dir * TT;
    const int t0 = dir ? (TT - 1) : 0;
    float p0 = g_pre0[((DOFF + t0) * BB + (b0 + 0)) * GG + tid];
    float p1 = g_pre0[((DOFF + t0) * BB + (b0 + 1)) * GG + tid];

    for (int s = 0; s < TT; ++s) {
        const int t = dir ? (TT - 1 - s) : s;
        float n0 = 0.f, n1 = 0.f;
        if (s + 1 < TT) {
            int tn = dir ? (TT - 2 - s) : (s + 1);
            n0 = g_pre0[((DOFF + tn) * BB + (b0 + 0)) * GG + tid];
            n1 = g_pre0[((DOFF + tn) * BB + (b0 + 1)) * GG + tid];
        }
        const float4* hq = (const float4*)hbuf;
        float acc0 = p0, acc1 = p1;
        HM2L(0, w0);  HM2L(1, w1);  HM2L(2, w2);   HM2L(3, w3);
        HM2L(4, w4);  HM2L(5, w5);  HM2L(6, w6);   HM2L(7, w7);
        HM2L(8, w8);  HM2L(9, w9);  HM2L(10, w10); HM2L(11, w11);
#pragma unroll
        for (int i = 0; i < 4; ++i) {
            float4 wq = wlds[i * 256 + tid];
            HM2L(12 + i, wq);
        }
        gact[0][tid] = is_g ? ftanh(acc0) : fsigm(acc0);
        gact[1][tid] = is_g ? ftanh(acc1) : fsigm(acc1);
        __syncthreads();   // gact ready; hbuf reads done

        if (tid < 128) {
            float ig = gact[cb][cj];
            float fg = gact[cb][HH + cj];
            float gg = gact[cb][2 * HH + cj];
            float og = gact[cb][3 * HH + cj];
            c_reg = fg * c_reg + ig * gg;
            float h = og * ftanh(c_reg);
            hbuf[tid] = h;   // tid == cb*64+cj
            g_h1[((size_t)t * BB + (b0 + cb)) * (2 * HH) + dir * HH + cj] = h;
        }
        __syncthreads();   // hbuf ready for next step's MAC

        p0 = n0; p1 = n1;
    }
}

// ---------------------------------------------------------------------------
// Layer-1 forward input pre-gates (unchanged from r10).
// ---------------------------------------------------------------------------
__global__ __launch_bounds__(256, 2) void pre_gemm1(
    const float* __restrict__ w_ih,   // [2][G][128] (dir 0 used)
    const float* __restrict__ b_ih,
    const float* __restrict__ b_hh)
{
    const int tid  = threadIdx.x;
    const int gl   = tid & 127;
    const int rg   = tid >> 7;
    const int b    = blockIdx.x >> 1;
    const int gate = (blockIdx.x & 1) * 128 + gl;

    __shared__ __align__(16) float4 w4[28 * 128];       // quads 0..27, 56 KB
    __shared__ __align__(16) float4 hstg[2][8 * 32];    // 8 t-rows x 32 q, dbuf 8 KB

    const float4* wsrc = (const float4*)w_ih + (size_t)gate * 32;
#pragma unroll
    for (int i = 0; i < 14; ++i) {
        int kq = rg * 14 + i;
        w4[kq * 128 + gl] = wsrc[kq];
    }
    float4 wr0 = wsrc[28], wr1 = wsrc[29], wr2 = wsrc[30], wr3 = wsrc[31];
    const float bias = b_ih[gate] + b_hh[gate];

    const int srow = tid >> 5, sq = tid & 31;
    hstg[0][srow * 32 + sq] =
        *((const float4*)(g_h1 + ((size_t)srow * BB + b) * 128) + sq);

    const size_t RS = (size_t)BB * GG;    // pre1 t-stride (floats)

    for (int tc = 0; tc < 64; ++tc) {
        const int cur = tc & 1;
        __syncthreads();   // hstg[cur] + w4 ready

        float4 vnext = make_float4(0.f, 0.f, 0.f, 0.f);
        if (tc + 1 < 64)
            vnext = *((const float4*)(g_h1 +
                      ((size_t)((tc + 1) * 8 + srow) * BB + b) * 128) + sq);

        const float4* hr0 = &hstg[cur][(rg * 4 + 0) * 32];
        const float4* hr1 = &hstg[cur][(rg * 4 + 1) * 32];
        const float4* hr2 = &hstg[cur][(rg * 4 + 2) * 32];
        const float4* hr3 = &hstg[cur][(rg * 4 + 3) * 32];

        float a0 = bias, a1 = bias, a2 = bias, a3 = bias;
#pragma unroll
        for (int kq = 0; kq < 28; ++kq) {
            float4 wq = w4[kq * 128 + gl];
            float4 q;
            q = hr0[kq]; a0 += q.x*wq.x + q.y*wq.y + q.z*wq.z + q.w*wq.w;
            q = hr1[kq]; a1 += q.x*wq.x + q.y*wq.y + q.z*wq.z + q.w*wq.w;
            q = hr2[kq]; a2 += q.x*wq.x + q.y*wq.y + q.z*wq.z + q.w*wq.w;
            q = hr3[kq]; a3 += q.x*wq.x + q.y*wq.y + q.z*wq.z + q.w*wq.w;
        }
        {
            float4 q;
            q = hr0[28]; a0 += q.x*wr0.x + q.y*wr0.y + q.z*wr0.z + q.w*wr0.w;
            q = hr1[28]; a1 += q.x*wr0.x + q.y*wr0.y + q.z*wr0.z + q.w*wr0.w;
            q = hr2[28]; a2 += q.x*wr0.x + q.y*wr0.y + q.z*wr0.z + q.w*wr0.w;
            q = hr3[28]; a3 += q.x*wr0.x + q.y*wr0.y + q.z*wr0.z + q.w*wr0.w;
            q = hr0[29]; a0 += q.x*wr1.x + q.y*wr1.y + q.z*wr1.z + q.w*wr1.w;
            q = hr1[29]; a1 += q.x*wr1.x + q.y*wr1.y + q.z*wr1.z + q.w*wr1.w;
            q = hr2[29]; a2 += q.x*wr1.x + q.y*wr1.y + q.z*wr1.z + q.w*wr1.w;
            q = hr3[29]; a3 += q.x*wr1.x + q.y*wr1.y + q.z*wr1.z + q.w*wr1.w;
            q = hr0[30]; a0 += q.x*wr2.x + q.y*wr2.y + q.z*wr2.z + q.w*wr2.w;
            q = hr1[30]; a1 += q.x*wr2.x + q.y*wr2.y + q.z*wr2.z + q.w*wr2.w;
            q = hr2[30]; a2 += q.x*wr2.x + q.y*wr2.y + q.z*wr2.z + q.w*wr2.w;
            q = hr3[30]; a3 += q.x*wr2.x + q.y*wr2.y + q.z*wr2.z + q.w*wr2.w;
            q = hr0[31]; a0 += q.x*wr3.x + q.y*wr3.y + q.z*wr3.z + q.w*wr3.w;
            q = hr1[31]; a1 += q.x*wr3.x + q.y*wr3.y + q.z*wr3.z + q.w*wr3.w;
            q = hr2[31]; a2 += q.x*wr3.x + q.y*wr3.y + q.z*wr3.z + q.w*wr3.w;
            q = hr3[31]; a3 += q.x*wr3.x + q.y*wr3.y + q.z*wr3.z + q.w*wr3.w;
        }
        {
            const int tb = tc * 8 + rg * 4;
            float* op = g_pre1 + ((size_t)tb * BB + b) * GG + gate;
            op[0 * RS] = a0; op[1 * RS] = a1; op[2 * RS] = a2; op[3 * RS] = a3;
        }
        if (tc + 1 < 64) hstg[1 - cur][srow * 32 + sq] = vnext;
    }
}

// ---------------------------------------------------------------------------
// Layer 1 forward scan, v3: LDS-broadcast operands. 1024 blocks x 256 thr,
// one batch per block. Same reg/LDS weight split as layer0_scan.
// ---------------------------------------------------------------------------
__global__ __launch_bounds__(256, 4) void lstm_layer1_fwd(
    const float* __restrict__ w_hh)   // [2][G][64] (dir 0 used)
{
    const int tid = threadIdx.x;
    const int b   = blockIdx.x;

    __shared__ __align__(16) float4 wlds[4 * 256];   // quads 12..15, 16 KB
    __shared__ float gact[GG];
    __shared__ __align__(16) float hbuf[64];

    const float4* wsrc = (const float4*)w_hh + (size_t)tid * 16;
    float4 w0 = wsrc[0],  w1 = wsrc[1],  w2 = wsrc[2],  w3 = wsrc[3],
           w4 = wsrc[4],  w5 = wsrc[5],  w6 = wsrc[6],  w7 = wsrc[7],
           w8 = wsrc[8],  w9 = wsrc[9],  w10 = wsrc[10], w11 = wsrc[11];
#pragma unroll
    for (int i = 0; i < 4; ++i) wlds[i * 256 + tid] = wsrc[12 + i];

    float c_reg = 0.f;
    const int cj = tid & 63;
    const bool is_g = ((tid >> 6) == 2);
    if (tid < 64) hbuf[tid] = 0.f;
    __syncthreads();   // wlds + hbuf ready

    float p0 = g_pre1[((size_t)0 * BB + b) * GG + tid];

    for (int t = 0; t < TT; ++t) {
        float n0 = 0.f;
        if (t + 1 < TT)
            n0 = g_pre1[((size_t)(t + 1) * BB + b) * GG + tid];

        const float4* hq = (const float4*)hbuf;
        float acc0 = p0;
        HM1L(0, w0);  HM1L(1, w1);  HM1L(2, w2);   HM1L(3, w3);
        HM1L(4, w4);  HM1L(5, w5);  HM1L(6, w6);   HM1L(7, w7);
        HM1L(8, w8);  HM1L(9, w9);  HM1L(10, w10); HM1L(11, w11);
#pragma unroll
        for (int i = 0; i < 4; ++i) {
            float4 wq = wlds[i * 256 + tid];
            HM1L(12 + i, wq);
        }
        gact[tid] = is_g ? ftanh(acc0) : fsigm(acc0);
        __syncthreads();   // gact ready; hbuf reads done

        if (tid < 64) {
            float ig = gact[cj];
            float fg = gact[HH + cj];
            float gg = gact[2 * HH + cj];
            float og = gact[3 * HH + cj];
            c_reg = fg * c_reg + ig * gg;
            float h = og * ftanh(c_reg);
            hbuf[tid] = h;
            if (t == TT - 1) g_hf[(size_t)b * HH + cj] = h;
        }
        __syncthreads();   // hbuf ready

        p0 = n0;
    }
}

// ---------------------------------------------------------------------------
// Layer 1 backward single step (zero state on h1[T-1]) + FC head.
// Unchanged from r10 (runs once; cost negligible).
// ---------------------------------------------------------------------------
#define FMAC4(W, P0, P1, P2, P3, K) do{                                   \
    float4 v_;                                                           \
    v_ = (P0)[K]; acc0 += W.x*v_.x; acc0 += W.y*v_.y; acc0 += W.z*v_.z; acc0 += W.w*v_.w; \
    v_ = (P1)[K]; acc1 += W.x*v_.x; acc1 += W.y*v_.y; acc1 += W.z*v_.z; acc1 += W.w*v_.w; \
    v_ = (P2)[K]; acc2 += W.x*v_.x; acc2 += W.y*v_.y; acc2 += W.z*v_.z; acc2 += W.w*v_.w; \
    v_ = (P3)[K]; acc3 += W.x*v_.x; acc3 += W.y*v_.y; acc3 += W.z*v_.z; acc3 += W.w*v_.w; \
}while(0)

__global__ __launch_bounds__(256, 2) void lstm_final(
    const float* __restrict__ w_ih,   // [2][G][128] (dir 1)
    const float* __restrict__ b_ih,
    const float* __restrict__ b_hh,
    const float* __restrict__ fc_w,   // [2][128]
    const float* __restrict__ fc_b,   // [2]
    float* __restrict__ out)          // [B][2]
{
    const int tid = threadIdx.x;
    const int b0  = blockIdx.x * 4;

    __shared__ __align__(16) float x_lds[4][128];
    __shared__ __align__(16) float gact[4][GG];
    __shared__ __align__(16) float last[4][128];

#pragma unroll
    for (int r = 0; r < 2; ++r) {
        int idx = tid + r * 256;
        int b = idx >> 7, col = idx & 127;
        x_lds[b][col] = g_h1[((size_t)(TT - 1) * BB + (b0 + b)) * 128 + col];
    }

    const float4* p = (const float4*)(w_ih + ((size_t)GG + tid) * 128);
    float4 w0 = p[0],  w1 = p[1],  w2 = p[2],  w3 = p[3],  w4 = p[4],  w5 = p[5],
           w6 = p[6],  w7 = p[7],  w8 = p[8],  w9 = p[9],  w10 = p[10], w11 = p[11],
           w12 = p[12], w13 = p[13], w14 = p[14], w15 = p[15], w16 = p[16], w17 = p[17],
           w18 = p[18], w19 = p[19], w20 = p[20], w21 = p[21], w22 = p[22], w23 = p[23],
           w24 = p[24], w25 = p[25], w26 = p[26], w27 = p[27], w28 = p[28], w29 = p[29],
           w30 = p[30], w31 = p[31];
    const float bias = b_ih[GG + tid] + b_hh[GG + tid];
    __syncthreads();

    const float4* xb0 = (const float4*)x_lds[0];
    const float4* xb1 = (const float4*)x_lds[1];
    const float4* xb2 = (const float4*)x_lds[2];
    const float4* xb3 = (const float4*)x_lds[3];

    float acc0 = bias, acc1 = bias, acc2 = bias, acc3 = bias;
    FMAC4(w0, xb0, xb1, xb2, xb3, 0);   FMAC4(w1, xb0, xb1, xb2, xb3, 1);
    FMAC4(w2, xb0, xb1, xb2, xb3, 2);   FMAC4(w3, xb0, xb1, xb2, xb3, 3);
    FMAC4(w4, xb0, xb1, xb2, xb3, 4);   FMAC4(w5, xb0, xb1, xb2, xb3, 5);
    FMAC4(w6, xb0, xb1, xb2, xb3, 6);   FMAC4(w7, xb0, xb1, xb2, xb3, 7);
    FMAC4(w8, xb0, xb1, xb2, xb3, 8);   FMAC4(w9, xb0, xb1, xb2, xb3, 9);
    FMAC4(w10, xb0, xb1, xb2, xb3, 10); FMAC4(w11, xb0, xb1, xb2, xb3, 11);
    FMAC4(w12, xb0, xb1, xb2, xb3, 12); FMAC4(w13, xb0, xb1, xb2, xb3, 13);
    FMAC4(w14, xb0, xb1, xb2, xb3, 14); FMAC4(w15, xb0, xb1, xb2, xb3, 15);
    FMAC4(w16, xb0, xb1, xb2, xb3, 16); FMAC4(w17, xb0, xb1, xb2, xb3, 17);
    FMAC4(w18, xb0, xb1, xb2, xb3, 18); FMAC4(w19, xb0, xb1, xb2, xb3, 19);
    FMAC4(w20, xb0, xb1, xb2, xb3, 20); FMAC4(w21, xb0, xb1, xb2, xb3, 21);
    FMAC4(w22, xb0, xb1, xb2, xb3, 22); FMAC4(w23, xb0, xb1, xb2, xb3, 23);
    FMAC4(w24, xb0, xb1, xb2, xb3, 24); FMAC4(w25, xb0, xb1, xb2, xb3, 25);
    FMAC4(w26, xb0, xb1, xb2, xb3, 26); FMAC4(w27, xb0, xb1, xb2, xb3, 27);
    FMAC4(w28, xb0, xb1, xb2, xb3, 28); FMAC4(w29, xb0, xb1, xb2, xb3, 29);
    FMAC4(w30, xb0, xb1, xb2, xb3, 30); FMAC4(w31, xb0, xb1, xb2, xb3, 31);

    const bool is_g = ((tid >> 6) == 2);
    gact[0][tid] = is_g ? ftanh(acc0) : fsigm(acc0);
    gact[1][tid] = is_g ? ftanh(acc1) : fsigm(acc1);
    gact[2][tid] = is_g ? ftanh(acc2) : fsigm(acc2);
    gact[3][tid] = is_g ? ftanh(acc3) : fsigm(acc3);
    __syncthreads();

    {
        const int cb = tid >> 6, cj = tid & 63;
        float ig = gact[cb][cj];
        float gg = gact[cb][2 * HH + cj];
        float og = gact[cb][3 * HH + cj];
        float c = ig * gg;
        float h = og * ftanh(c);
        last[cb][HH + cj] = h;
        last[cb][cj] = g_hf[(size_t)(b0 + cb) * HH + cj];
    }
    __syncthreads();

    if (tid < 8) {
        int b = tid >> 1, o = tid & 1;
        float a = fc_b[o];
#pragma unroll
        for (int j = 0; j < 128; ++j) a += fc_w[o * 128 + j] * last[b][j];
        out[(size_t)(b0 + b) * 2 + o] = a;
    }
}

extern "C" void kernel_launch(void* const* d_in, const int* in_sizes, int n_in,
                              void* d_out, int out_size, void* d_ws, size_t ws_size,
                              hipStream_t stream) {
    const float* x     = (const float*)d_in[0];
    const float* w_ih0 = (const float*)d_in[1];
    const float* w_hh0 = (const float*)d_in[2];
    const float* b_ih0 = (const float*)d_in[3];
    const float* b_hh0 = (const float*)d_in[4];
    const float* w_ih1 = (const float*)d_in[5];
    const float* w_hh1 = (const float*)d_in[6];
    const float* b_ih1 = (const float*)d_in[7];
    const float* b_hh1 = (const float*)d_in[8];
    const float* fc_w  = (const float*)d_in[9];
    const float* fc_b  = (const float*)d_in[10];
    float* out = (float*)d_out;

    pre_gemm0<<<2048, 256, 0, stream>>>(x, w_ih0, b_ih0, b_hh0);
    lstm_layer0_scan<<<1024, 256, 0, stream>>>(w_hh0);
    pre_gemm1<<<2048, 256, 0, stream>>>(w_ih1, b_ih1, b_hh1);
    lstm_layer1_fwd<<<1024, 256, 0, stream>>>(w_hh1);
    lstm_final<<<256, 256, 0, stream>>>(w_ih1, b_ih1, b_hh1, fc_w, fc_b, out);
}